// Round 4
// baseline (1221.637 us; speedup 1.0000x reference)
//
#include <hip/hip_runtime.h>
#include <stdint.h>

typedef unsigned short u16;
typedef unsigned int u32;
typedef short bf16x8 __attribute__((ext_vector_type(8)));
typedef float f32x4 __attribute__((ext_vector_type(4)));

#define E_ 8
#define H_ 2048
#define F_ 4096
#define T_ 16384
#define TE_ 2048

#define WAITV(n) asm volatile("s_waitcnt vmcnt(" #n ")" ::: "memory")
#define BARF                              \
  do {                                    \
    asm volatile("" ::: "memory");        \
    __builtin_amdgcn_s_barrier();         \
    asm volatile("" ::: "memory");        \
  } while (0)

__device__ __forceinline__ u16 f2bf(float f) {
  u32 u = __builtin_bit_cast(u32, f);
  u32 r = (u + 0x7FFFu + ((u >> 16) & 1u)) >> 16;  // RNE
  return (u16)r;
}

__device__ __forceinline__ void gload16(const u16* g, u16* l) {
  __builtin_amdgcn_global_load_lds(
      (__attribute__((address_space(1))) void*)g,
      (__attribute__((address_space(3))) void*)l, 16, 0, 0);
}

__device__ __forceinline__ void mfma_b(f32x4& acc, bf16x8 a, bf16x8 b) {
  asm volatile("v_mfma_f32_16x16x32_bf16 %0, %1, %2, %0"
               : "+v"(acc)
               : "v"(a), "v"(b));
}

// ---------- fp32 -> bf16 convert ----------

__global__ __launch_bounds__(256) void cvt_kernel(const float* __restrict__ src,
                                                  u16* __restrict__ dst,
                                                  long n4) {
  long i = (long)blockIdx.x * blockDim.x + threadIdx.x;
  long stride = (long)gridDim.x * blockDim.x;
  const float4* s4 = (const float4*)src;
  uint2* d4 = (uint2*)dst;
  for (; i < n4; i += stride) {
    float4 v = s4[i];
    uint2 o;
    o.x = (u32)f2bf(v.x) | ((u32)f2bf(v.y) << 16);
    o.y = (u32)f2bf(v.z) | ((u32)f2bf(v.w) << 16);
    d4[i] = o;
  }
}

// Within-expert XCD swizzle: expert stays in blockIdx.z (sequential rounds);
// XCD k takes row-panel by=k and sweeps bx, so A-panels are XCD-L2-resident
// and all XCDs read the SAME bx weight stream concurrently (L3-shared, one
// HBM fetch). Requires nx*ny % 8 == 0 (true for all grids used here).
__device__ __forceinline__ void swz2d(int& bx, int& by) {
  const int nx = gridDim.x, ny = gridDim.y;
  int lin2 = blockIdx.x + nx * blockIdx.y;
  const int npe = nx * ny;
  int swz = (lin2 & 7) * (npe >> 3) + (lin2 >> 3);
  bx = swz % nx;
  by = swz / nx;
}

// ============ 8-phase 256x256 GEMM1 (fused SiLU) ============
// Block: 256 token rows x (128 gate + 128 up interleaved) cols, BK=64.
// 8 waves 2Mx4N; wave tile 128x64. LDS 128 KiB: [2 buf][A,B][2 kh][16 chunks
// x 1KiB lane-linear]. B-chunk c: isUp=c&1, pair=c>>1 (gate/up interleave).

__global__ __launch_bounds__(512, 2) void gemm1_silu(
    const u16* __restrict__ Xb, const u16* __restrict__ Wgu,
    u16* __restrict__ Hid) {
  int bx, by;
  swz2d(bx, by);
  const int z = blockIdx.z;
  Xb += (size_t)z * TE_ * H_;
  Wgu += (size_t)z * 2 * F_ * H_;
  Hid += (size_t)z * TE_ * F_;

  const int tid = threadIdx.x, w = tid >> 6, lane = tid & 63;
  const int wr = w >> 2, wc = w & 3;
  const int r15 = lane & 15, g4 = lane >> 4;

  __shared__ __attribute__((aligned(16))) u16 lds[65536];
  // elem offset: buf*32768 + op*16384 + kh*8192 + chunk*512 + lane*8

  const u16* gA = Xb + (size_t)(by * 256 + r15) * H_ + g4 * 8;
  const u16* gB =
      Wgu + (size_t)(((w & 1) ? F_ : 0) + bx * 128 + r15) * H_ + g4 * 8;

  auto stA = [&](int t, int kh, int buf) {
#pragma unroll
    for (int i = 0; i < 2; ++i) {
      const int c = i * 8 + w;
      gload16(gA + (size_t)(c * 16) * H_ + t * 64 + kh * 32,
              lds + buf * 32768 + kh * 8192 + c * 512);
    }
  };
  auto stB = [&](int t, int kh, int buf) {
#pragma unroll
    for (int i = 0; i < 2; ++i) {
      const int c = i * 8 + w;
      gload16(gB + (size_t)((i * 4 + (w >> 1)) * 16) * H_ + t * 64 + kh * 32,
              lds + buf * 32768 + 16384 + kh * 8192 + c * 512);
    }
  };

  const u16* ldsA = lds + lane * 8;
  const u16* ldsB = lds + 16384 + lane * 8;

  f32x4 acc[8][4] = {};
  bf16x8 a[4], b[4];

  auto dsB = [&](int buf, int kh) {
#pragma unroll
    for (int ni = 0; ni < 4; ++ni)
      b[ni] =
          *(const bf16x8*)&ldsB[buf * 32768 + kh * 8192 + (wc * 4 + ni) * 512];
  };
  auto dsA = [&](int buf, int kh, int mh) {
#pragma unroll
    for (int mi = 0; mi < 4; ++mi)
      a[mi] = *(const bf16x8*)&ldsA[buf * 32768 + kh * 8192 +
                                    (wr * 8 + mh * 4 + mi) * 512];
  };
  auto mm = [&](int mh) {
    __builtin_amdgcn_s_setprio(1);
#pragma unroll
    for (int mi = 0; mi < 4; ++mi)
#pragma unroll
      for (int ni = 0; ni < 4; ++ni) mfma_b(acc[mh * 4 + mi][ni], a[mi], b[ni]);
    __builtin_amdgcn_s_setprio(0);
  };

  // prologue: tile0 all 4 halves, tile1 {Bk0, Ak0, Bk1}
  stB(0, 0, 0); stA(0, 0, 0); stB(0, 1, 0); stA(0, 1, 0);
  stB(1, 0, 1); stA(1, 0, 1); stB(1, 1, 1);
  WAITV(6);
  BARF;

  const int NT = H_ / 64;  // 32
  for (int t = 0; t <= NT - 4; t += 2) {
    dsB(0, 0); dsA(0, 0, 0); stA(t + 1, 1, 1);           BARF; mm(0); BARF;
    dsA(0, 0, 1);            stB(t + 2, 0, 0);           BARF; mm(1); BARF;
    dsB(0, 1); dsA(0, 1, 0); stA(t + 2, 0, 0);           BARF; mm(0); BARF;
    dsA(0, 1, 1);            stB(t + 2, 1, 0); WAITV(6); BARF; mm(1); BARF;
    dsB(1, 0); dsA(1, 0, 0); stA(t + 2, 1, 0);           BARF; mm(0); BARF;
    dsA(1, 0, 1);            stB(t + 3, 0, 1);           BARF; mm(1); BARF;
    dsB(1, 1); dsA(1, 1, 0); stA(t + 3, 0, 1);           BARF; mm(0); BARF;
    dsA(1, 1, 1);            stB(t + 3, 1, 1); WAITV(6); BARF; mm(1); BARF;
  }
  // peeled last iteration (tiles NT-2 / NT-1)
  dsB(0, 0); dsA(0, 0, 0); stA(NT - 1, 1, 1); BARF; mm(0); BARF;
  dsA(0, 0, 1);                               BARF; mm(1); BARF;
  dsB(0, 1); dsA(0, 1, 0);                    BARF; mm(0); BARF;
  dsA(0, 1, 1);            WAITV(0);          BARF; mm(1); BARF;
  dsB(1, 0); dsA(1, 0, 0);                    BARF; mm(0); BARF;
  dsA(1, 0, 1);                               BARF; mm(1); BARF;
  dsB(1, 1); dsA(1, 1, 0);                    BARF; mm(0); BARF;
  dsA(1, 1, 1);                               BARF; mm(1);

  // epilogue: silu(gate)*up -> bf16
  const int row0 = by * 256 + wr * 128 + g4 * 4;
  const int colb = bx * 128 + wc * 32 + r15;
#pragma unroll
  for (int mI = 0; mI < 8; ++mI)
#pragma unroll
    for (int k = 0; k < 2; ++k)
#pragma unroll
      for (int j = 0; j < 4; ++j) {
        float g = acc[mI][2 * k][j];
        float u = acc[mI][2 * k + 1][j];
        float h = (g / (1.f + __expf(-g))) * u;
        Hid[(size_t)(row0 + mI * 16 + j) * F_ + colb + k * 16] = f2bf(h);
      }
}

// ============ 8-phase 256x256 GEMM2 (fp32 out) ============

__global__ __launch_bounds__(512, 2) void gemm2_down(
    const u16* __restrict__ Hd, const u16* __restrict__ Wd,
    float* __restrict__ Out) {
  int bx, by;
  swz2d(bx, by);
  const int z = blockIdx.z;
  Hd += (size_t)z * TE_ * F_;
  Wd += (size_t)z * H_ * F_;
  Out += (size_t)z * TE_ * H_;

  const int tid = threadIdx.x, w = tid >> 6, lane = tid & 63;
  const int wr = w >> 2, wc = w & 3;
  const int r15 = lane & 15, g4 = lane >> 4;

  __shared__ __attribute__((aligned(16))) u16 lds[65536];

  const u16* gA = Hd + (size_t)(by * 256 + r15) * F_ + g4 * 8;
  const u16* gB = Wd + (size_t)(bx * 256 + r15) * F_ + g4 * 8;

  auto stA = [&](int t, int kh, int buf) {
#pragma unroll
    for (int i = 0; i < 2; ++i) {
      const int c = i * 8 + w;
      gload16(gA + (size_t)(c * 16) * F_ + t * 64 + kh * 32,
              lds + buf * 32768 + kh * 8192 + c * 512);
    }
  };
  auto stB = [&](int t, int kh, int buf) {
#pragma unroll
    for (int i = 0; i < 2; ++i) {
      const int c = i * 8 + w;
      gload16(gB + (size_t)(c * 16) * F_ + t * 64 + kh * 32,
              lds + buf * 32768 + 16384 + kh * 8192 + c * 512);
    }
  };

  const u16* ldsA = lds + lane * 8;
  const u16* ldsB = lds + 16384 + lane * 8;

  f32x4 acc[8][4] = {};
  bf16x8 a[4], b[4];

  auto dsB = [&](int buf, int kh) {
#pragma unroll
    for (int ni = 0; ni < 4; ++ni)
      b[ni] =
          *(const bf16x8*)&ldsB[buf * 32768 + kh * 8192 + (wc * 4 + ni) * 512];
  };
  auto dsA = [&](int buf, int kh, int mh) {
#pragma unroll
    for (int mi = 0; mi < 4; ++mi)
      a[mi] = *(const bf16x8*)&ldsA[buf * 32768 + kh * 8192 +
                                    (wr * 8 + mh * 4 + mi) * 512];
  };
  auto mm = [&](int mh) {
    __builtin_amdgcn_s_setprio(1);
#pragma unroll
    for (int mi = 0; mi < 4; ++mi)
#pragma unroll
      for (int ni = 0; ni < 4; ++ni) mfma_b(acc[mh * 4 + mi][ni], a[mi], b[ni]);
    __builtin_amdgcn_s_setprio(0);
  };

  stB(0, 0, 0); stA(0, 0, 0); stB(0, 1, 0); stA(0, 1, 0);
  stB(1, 0, 1); stA(1, 0, 1); stB(1, 1, 1);
  WAITV(6);
  BARF;

  const int NT = F_ / 64;  // 64
  for (int t = 0; t <= NT - 4; t += 2) {
    dsB(0, 0); dsA(0, 0, 0); stA(t + 1, 1, 1);           BARF; mm(0); BARF;
    dsA(0, 0, 1);            stB(t + 2, 0, 0);           BARF; mm(1); BARF;
    dsB(0, 1); dsA(0, 1, 0); stA(t + 2, 0, 0);           BARF; mm(0); BARF;
    dsA(0, 1, 1);            stB(t + 2, 1, 0); WAITV(6); BARF; mm(1); BARF;
    dsB(1, 0); dsA(1, 0, 0); stA(t + 2, 1, 0);           BARF; mm(0); BARF;
    dsA(1, 0, 1);            stB(t + 3, 0, 1);           BARF; mm(1); BARF;
    dsB(1, 1); dsA(1, 1, 0); stA(t + 3, 0, 1);           BARF; mm(0); BARF;
    dsA(1, 1, 1);            stB(t + 3, 1, 1); WAITV(6); BARF; mm(1); BARF;
  }
  dsB(0, 0); dsA(0, 0, 0); stA(NT - 1, 1, 1); BARF; mm(0); BARF;
  dsA(0, 0, 1);                               BARF; mm(1); BARF;
  dsB(0, 1); dsA(0, 1, 0);                    BARF; mm(0); BARF;
  dsA(0, 1, 1);            WAITV(0);          BARF; mm(1); BARF;
  dsB(1, 0); dsA(1, 0, 0);                    BARF; mm(0); BARF;
  dsA(1, 0, 1);                               BARF; mm(1); BARF;
  dsB(1, 1); dsA(1, 1, 0);                    BARF; mm(0); BARF;
  dsA(1, 1, 1);                               BARF; mm(1);

  const int row0 = by * 256 + wr * 128 + g4 * 4;
  const int col0 = bx * 256 + wc * 64 + r15;
#pragma unroll
  for (int mI = 0; mI < 8; ++mI)
#pragma unroll
    for (int ni = 0; ni < 4; ++ni)
#pragma unroll
      for (int j = 0; j < 4; ++j)
        Out[(size_t)(row0 + mI * 16 + j) * H_ + col0 + ni * 16] =
            acc[mI][ni][j];
}

// ---------- host ----------

extern "C" void kernel_launch(void* const* d_in, const int* in_sizes, int n_in,
                              void* d_out, int out_size, void* d_ws,
                              size_t ws_size, hipStream_t stream) {
  (void)in_sizes;
  (void)n_in;
  (void)out_size;
  const float* x = (const float*)d_in[0];
  const float* wgu = (const float*)d_in[1];
  const float* wdn = (const float*)d_in[2];
  float* out = (float*)d_out;
  u16* ws = (u16*)d_ws;

  const size_t xbN = (size_t)T_ * H_;
  const size_t wguN = (size_t)E_ * 2 * F_ * H_;
  const size_t wdnN = (size_t)E_ * H_ * F_;
  const size_t hidN = (size_t)T_ * F_;
  const size_t fullBytes = (xbN + wguN + wdnN + hidN) * 2;  // 576 MiB

  dim3 cblk(256), gblk(512);

  if (ws_size >= fullBytes) {
    u16* xb = ws;
    u16* wgub = xb + xbN;
    u16* wdnb = wgub + wguN;
    u16* hid = wdnb + wdnN;
    cvt_kernel<<<2048, cblk, 0, stream>>>(x, xb, (long)(xbN / 4));
    cvt_kernel<<<4096, cblk, 0, stream>>>(wgu, wgub, (long)(wguN / 4));
    cvt_kernel<<<4096, cblk, 0, stream>>>(wdn, wdnb, (long)(wdnN / 4));
    gemm1_silu<<<dim3(F_ / 128, TE_ / 256, E_), gblk, 0, stream>>>(xb, wgub,
                                                                   hid);
    gemm2_down<<<dim3(H_ / 256, TE_ / 256, E_), gblk, 0, stream>>>(hid, wdnb,
                                                                   out);
  } else {
    u16* xb = ws;
    u16* wgub = xb + (size_t)TE_ * H_;
    u16* wdnb = wgub + (size_t)2 * F_ * H_;
    u16* hid = wdnb + (size_t)H_ * F_;
    for (int e = 0; e < E_; ++e) {
      cvt_kernel<<<1024, cblk, 0, stream>>>(x + (size_t)e * TE_ * H_, xb,
                                            (long)((size_t)TE_ * H_ / 4));
      cvt_kernel<<<2048, cblk, 0, stream>>>(wgu + (size_t)e * 2 * F_ * H_, wgub,
                                            (long)((size_t)2 * F_ * H_ / 4));
      cvt_kernel<<<2048, cblk, 0, stream>>>(wdn + (size_t)e * H_ * F_, wdnb,
                                            (long)((size_t)H_ * F_ / 4));
      gemm1_silu<<<dim3(F_ / 128, TE_ / 256, 1), gblk, 0, stream>>>(xb, wgub,
                                                                    hid);
      gemm2_down<<<dim3(H_ / 256, TE_ / 256, 1), gblk, 0, stream>>>(
          hid, wdnb, out + (size_t)e * TE_ * H_);
    }
  }
}

// Round 5
// 1185.723 us; speedup vs baseline: 1.0303x; 1.0303x over previous
//
#include <hip/hip_runtime.h>
#include <stdint.h>

typedef unsigned short u16;
typedef unsigned int u32;
typedef short bf16x8 __attribute__((ext_vector_type(8)));
typedef float f32x4 __attribute__((ext_vector_type(4)));

#define E_ 8
#define H_ 2048
#define F_ 4096
#define T_ 16384
#define TE_ 2048

#define WAITV(n) asm volatile("s_waitcnt vmcnt(" #n ")" ::: "memory")
#define BARF                       \
  do {                             \
    asm volatile("" ::: "memory"); \
    __builtin_amdgcn_s_barrier();  \
    asm volatile("" ::: "memory"); \
  } while (0)

__device__ __forceinline__ u16 f2bf(float f) {
  u32 u = __builtin_bit_cast(u32, f);
  u32 r = (u + 0x7FFFu + ((u >> 16) & 1u)) >> 16;  // RNE
  return (u16)r;
}

__device__ __forceinline__ void gload16(const u16* g, u16* l) {
  __builtin_amdgcn_global_load_lds(
      (__attribute__((address_space(1))) void*)g,
      (__attribute__((address_space(3))) void*)l, 16, 0, 0);
}

__device__ __forceinline__ void mfma_b(f32x4& acc, bf16x8 a, bf16x8 b) {
  asm volatile("v_mfma_f32_16x16x32_bf16 %0, %1, %2, %0"
               : "+v"(acc)
               : "v"(a), "v"(b));
}

// ---------- fp32 -> bf16 convert ----------

__global__ __launch_bounds__(256) void cvt_kernel(const float* __restrict__ src,
                                                  u16* __restrict__ dst,
                                                  long n4) {
  long i = (long)blockIdx.x * blockDim.x + threadIdx.x;
  long stride = (long)gridDim.x * blockDim.x;
  const float4* s4 = (const float4*)src;
  uint2* d4 = (uint2*)dst;
  for (; i < n4; i += stride) {
    float4 v = s4[i];
    uint2 o;
    o.x = (u32)f2bf(v.x) | ((u32)f2bf(v.y) << 16);
    o.y = (u32)f2bf(v.z) | ((u32)f2bf(v.w) << 16);
    d4[i] = o;
  }
}

// ============ GEMM1 fused (shared-A): tile 256 rows x 128 hidden ============
// hidden = silu(x@Wg^T) * (x@Wu^T). BK=64, ring-2 LDS (128 KiB), counted
// vmcnt(8). 8 waves: rq=w>>1 row-quarter (64 rows), ch=w&1 col-half (64 cols).
// Each wave: 24 ds_read_b128 -> 64 MFMA per K-tile (gate+up share A-frags).
// LDS chunk layout: chunk=16 rows x 32 k = 512 elems, lane-linear (0-conflict,
// global_load_lds-compatible). A chunks c=rg*2+ks (rg=row/16); B: gate rg 0-7,
// up rg 8-15.

__global__ __launch_bounds__(512, 2) void gemm1_silu(
    const u16* __restrict__ Xb, const u16* __restrict__ Wgu,
    u16* __restrict__ Hid) {
  const int bx = blockIdx.x;  // hidden-col tile (128)
  const int by = blockIdx.y;  // row tile (256)
  const int z = blockIdx.z;
  Xb += (size_t)z * TE_ * H_;
  Wgu += (size_t)z * 2 * F_ * H_;
  Hid += (size_t)z * TE_ * F_;

  const int tid = threadIdx.x, w = tid >> 6, lane = tid & 63;
  const int rq = w >> 1, ch = w & 1;
  const int r15 = lane & 15, g4 = lane >> 4;

  __shared__ __attribute__((aligned(16))) u16 lds[65536];  // 128 KiB

  const u16* gA = Xb + (size_t)(by * 256 + r15) * H_ + g4 * 8;
  const u16* gBg = Wgu + (size_t)(bx * 128 + r15) * H_ + g4 * 8;
  const u16* gBu = Wgu + (size_t)(F_ + bx * 128 + r15) * H_ + g4 * 8;

  auto stage = [&](int t, int buf) {
    u16* L = lds + buf * 32768;
    const int kb = t * 64;
#pragma unroll
    for (int i = 0; i < 4; ++i) {
      const int c = i * 8 + w, rg = c >> 1, ks = c & 1;
      gload16(gA + (size_t)(rg * 16) * H_ + kb + ks * 32,
              L + c * 512 + lane * 8);
    }
#pragma unroll
    for (int i = 0; i < 2; ++i) {  // gate rows (rg 0..7)
      const int c = i * 8 + w, rg = c >> 1, ks = c & 1;
      gload16(gBg + (size_t)(rg * 16) * H_ + kb + ks * 32,
              L + 16384 + c * 512 + lane * 8);
    }
#pragma unroll
    for (int i = 2; i < 4; ++i) {  // up rows (rg 8..15 -> up 0..7)
      const int c = i * 8 + w, rg = (c >> 1) - 8, ks = c & 1;
      gload16(gBu + (size_t)(rg * 16) * H_ + kb + ks * 32,
              L + 16384 + c * 512 + lane * 8);
    }
  };

  f32x4 accG[4][4] = {};
  f32x4 accU[4][4] = {};

  auto comp = [&](int buf) {
    const u16* LA = lds + buf * 32768 + lane * 8;
    const u16* LB = LA + 16384;
#pragma unroll
    for (int ks = 0; ks < 2; ++ks) {
      bf16x8 a[4], bg[4], bu[4];
#pragma unroll
      for (int mi = 0; mi < 4; ++mi)
        a[mi] = *(const bf16x8*)&LA[((rq * 4 + mi) * 2 + ks) * 512];
#pragma unroll
      for (int ni = 0; ni < 4; ++ni) {
        bg[ni] = *(const bf16x8*)&LB[((ch * 4 + ni) * 2 + ks) * 512];
        bu[ni] = *(const bf16x8*)&LB[((8 + ch * 4 + ni) * 2 + ks) * 512];
      }
      __builtin_amdgcn_s_setprio(1);
#pragma unroll
      for (int mi = 0; mi < 4; ++mi)
#pragma unroll
        for (int ni = 0; ni < 4; ++ni) {
          mfma_b(accG[mi][ni], a[mi], bg[ni]);
          mfma_b(accU[mi][ni], a[mi], bu[ni]);
        }
      __builtin_amdgcn_s_setprio(0);
    }
  };

  const int NT = H_ / 64;  // 32
  stage(0, 0);
  stage(1, 1);
  for (int t = 0; t < NT - 1; ++t) {
    WAITV(8);  // tile t landed (8 loads/wave/stage; t+1 stays in flight)
    BARF;
    comp(t & 1);
    BARF;  // all waves done reading buf (t&1) -> safe to overwrite
    if (t + 2 < NT) stage(t + 2, t & 1);
  }
  WAITV(0);
  BARF;
  comp((NT - 1) & 1);

  // epilogue: silu(gate)*up -> bf16
  const int row0 = by * 256 + rq * 64 + g4 * 4;
  const int col0 = bx * 128 + ch * 64 + r15;
#pragma unroll
  for (int mi = 0; mi < 4; ++mi)
#pragma unroll
    for (int ni = 0; ni < 4; ++ni)
#pragma unroll
      for (int j = 0; j < 4; ++j) {
        float g = accG[mi][ni][j];
        float u = accU[mi][ni][j];
        float h = (g / (1.f + __expf(-g))) * u;
        Hid[(size_t)(row0 + mi * 16 + j) * F_ + col0 + ni * 16] = f2bf(h);
      }
}

// ---------- GEMM2: out = hidden @ w_down^T (fp32 out) ----------
// Tile: 256 rows x 128 cols, BK=64, ring-3 LDS, counted vmcnt. (round-2 ver.)

__global__ __launch_bounds__(512) void gemm2_down(const u16* __restrict__ Hd,
                                                  const u16* __restrict__ Wd,
                                                  float* __restrict__ Out,
                                                  long sH, long sW, long sO) {
  const int z = blockIdx.z;
  Hd += (long)z * sH;
  Wd += (long)z * sW;
  Out += (long)z * sO;

  const int bx = blockIdx.x;  // H-col tile (128)
  const int by = blockIdx.y;  // row tile (256)
  const int tid = threadIdx.x;
  const int w = tid >> 6;
  const int lane = tid & 63;
  const int wr = w >> 1, wc = w & 1;

  // per-buf: A[256][64] (16384) + B[128][64] (8192)
  __shared__ __attribute__((aligned(16))) u16 lds[3 * 24576];

  const int srow = (w << 3) + (lane >> 3);
  const int scol = (((lane & 7) ^ (lane >> 3)) << 3);
  const u16* gA = Hd + (size_t)((by << 8) + srow) * F_ + scol;
  const u16* gB = Wd + (size_t)((bx << 7) + srow) * F_ + scol;

  auto stage = [&](int t, int buf) {
    u16* L = &lds[buf * 24576];
    const int ko = t << 6;
    const int wb = w << 3;
#pragma unroll
    for (int i = 0; i < 4; ++i)
      gload16(gA + (size_t)(i * 64) * F_ + ko, &L[((i << 6) + wb) << 6]);
#pragma unroll
    for (int i = 0; i < 2; ++i)
      gload16(gB + (size_t)(i * 64) * F_ + ko,
              &L[16384 + (((i << 6) + wb) << 6)]);
  };

  f32x4 acc[4][4] = {};
  const int fr = lane & 15, q = lane >> 4, l7 = lane & 7;

  auto comp = [&](int buf) {
    const u16* L = &lds[buf * 24576];
    bf16x8 a[4][2], b[4][2];
#pragma unroll
    for (int ni = 0; ni < 4; ++ni)
#pragma unroll
      for (int ks = 0; ks < 2; ++ks) {
        int r = (wc << 6) + (ni << 4) + fr;
        b[ni][ks] =
            *(const bf16x8*)&L[16384 + (r << 6) + ((((ks << 2) + q) ^ l7) << 3)];
      }
#pragma unroll
    for (int mi = 0; mi < 4; ++mi)
#pragma unroll
      for (int ks = 0; ks < 2; ++ks) {
        int r = (wr << 6) + (mi << 4) + fr;
        a[mi][ks] = *(const bf16x8*)&L[(r << 6) + ((((ks << 2) + q) ^ l7) << 3)];
      }
    __builtin_amdgcn_s_setprio(1);
#pragma unroll
    for (int mi = 0; mi < 4; ++mi)
#pragma unroll
      for (int ni = 0; ni < 4; ++ni)
#pragma unroll
        for (int ks = 0; ks < 2; ++ks)
          mfma_b(acc[mi][ni], a[mi][ks], b[ni][ks]);
    __builtin_amdgcn_s_setprio(0);
  };

  const int NT = F_ / 64;  // 64
  stage(0, 0);
  stage(1, 1);
  int b0 = 0, b1 = 1, b2 = 2;
  for (int t = 0; t < NT - 2; ++t) {
    stage(t + 2, b2);
    WAITV(12);
    BARF;
    comp(b0);
    BARF;
    int tmp = b0; b0 = b1; b1 = b2; b2 = tmp;
  }
  WAITV(6); BARF;
  comp(b0);
  BARF;
  WAITV(0); BARF;
  comp(b1);

  const int row0 = (by << 8) + (wr << 6) + (q << 2);
  const int col0 = (bx << 7) + (wc << 6) + fr;
#pragma unroll
  for (int mi = 0; mi < 4; ++mi)
#pragma unroll
    for (int ni = 0; ni < 4; ++ni)
#pragma unroll
      for (int j = 0; j < 4; ++j)
        Out[(size_t)(row0 + (mi << 4) + j) * H_ + col0 + (ni << 4)] =
            acc[mi][ni][j];
}

// ---------- host ----------

extern "C" void kernel_launch(void* const* d_in, const int* in_sizes, int n_in,
                              void* d_out, int out_size, void* d_ws,
                              size_t ws_size, hipStream_t stream) {
  (void)in_sizes;
  (void)n_in;
  (void)out_size;
  const float* x = (const float*)d_in[0];
  const float* wgu = (const float*)d_in[1];
  const float* wdn = (const float*)d_in[2];
  float* out = (float*)d_out;
  u16* ws = (u16*)d_ws;

  const size_t xbN = (size_t)T_ * H_;
  const size_t wguN = (size_t)E_ * 2 * F_ * H_;
  const size_t wdnN = (size_t)E_ * H_ * F_;
  const size_t hidN = (size_t)T_ * F_;
  const size_t fullBytes = (xbN + wguN + wdnN + hidN) * 2;  // 576 MiB

  dim3 cblk(256), gblk(512);

  if (ws_size >= fullBytes) {
    u16* xb = ws;
    u16* wgub = xb + xbN;
    u16* wdnb = wgub + wguN;
    u16* hid = wdnb + wdnN;
    cvt_kernel<<<2048, cblk, 0, stream>>>(x, xb, (long)(xbN / 4));
    cvt_kernel<<<4096, cblk, 0, stream>>>(wgu, wgub, (long)(wguN / 4));
    cvt_kernel<<<4096, cblk, 0, stream>>>(wdn, wdnb, (long)(wdnN / 4));
    gemm1_silu<<<dim3(F_ / 128, TE_ / 256, E_), gblk, 0, stream>>>(xb, wgub,
                                                                   hid);
    gemm2_down<<<dim3(H_ / 128, TE_ / 256, E_), gblk, 0, stream>>>(
        hid, wdnb, out, (long)TE_ * F_, (long)H_ * F_, (long)TE_ * H_);
  } else {
    u16* xb = ws;
    u16* wgub = xb + (size_t)TE_ * H_;
    u16* wdnb = wgub + (size_t)2 * F_ * H_;
    u16* hid = wdnb + (size_t)H_ * F_;
    for (int e = 0; e < E_; ++e) {
      cvt_kernel<<<1024, cblk, 0, stream>>>(x + (size_t)e * TE_ * H_, xb,
                                            (long)((size_t)TE_ * H_ / 4));
      cvt_kernel<<<2048, cblk, 0, stream>>>(wgu + (size_t)e * 2 * F_ * H_, wgub,
                                            (long)((size_t)2 * F_ * H_ / 4));
      cvt_kernel<<<2048, cblk, 0, stream>>>(wdn + (size_t)e * H_ * F_, wdnb,
                                            (long)((size_t)H_ * F_ / 4));
      gemm1_silu<<<dim3(F_ / 128, TE_ / 256, 1), gblk, 0, stream>>>(xb, wgub,
                                                                    hid);
      gemm2_down<<<dim3(H_ / 128, TE_ / 256, 1), gblk, 0, stream>>>(
          hid, wdnb, out + (size_t)e * TE_ * H_, 0, 0, 0);
    }
  }
}

// Round 6
// 1175.016 us; speedup vs baseline: 1.0397x; 1.0091x over previous
//
#include <hip/hip_runtime.h>
#include <stdint.h>

typedef unsigned short u16;
typedef unsigned int u32;
typedef short bf16x8 __attribute__((ext_vector_type(8)));
typedef float f32x16 __attribute__((ext_vector_type(16)));

#define E_ 8
#define H_ 2048
#define F_ 4096
#define T_ 16384
#define TE_ 2048

#define WAITV(n) asm volatile("s_waitcnt vmcnt(" #n ")" ::: "memory")
#define BARF                       \
  do {                             \
    asm volatile("" ::: "memory"); \
    __builtin_amdgcn_s_barrier();  \
    asm volatile("" ::: "memory"); \
  } while (0)

__device__ __forceinline__ u16 f2bf(float f) {
  u32 u = __builtin_bit_cast(u32, f);
  u32 r = (u + 0x7FFFu + ((u >> 16) & 1u)) >> 16;  // RNE
  return (u16)r;
}

__device__ __forceinline__ void gload16(const u16* g, u16* l) {
  __builtin_amdgcn_global_load_lds(
      (__attribute__((address_space(1))) void*)g,
      (__attribute__((address_space(3))) void*)l, 16, 0, 0);
}

// D(32x32) += A(32x16) * B(16x32), bf16 in / f32 acc.
// A/B: lane holds row=lane&31, k=(lane>>5)*8+j. C/D: col=lane&31,
// row=(r&3)+8*(r>>2)+4*(lane>>5)  [guide m74/m101 verified].
__device__ __forceinline__ void mfma32(f32x16& acc, bf16x8 a, bf16x8 b) {
  asm volatile("v_mfma_f32_32x32x16_bf16 %0, %1, %2, %0"
               : "+v"(acc)
               : "v"(a), "v"(b));
}

// ---------- fused fp32 -> bf16 convert (3 segments, 1 launch) ----------

__global__ __launch_bounds__(256) void cvt3_kernel(
    const float* __restrict__ s0, const float* __restrict__ s1,
    const float* __restrict__ s2, u16* __restrict__ dst, long n0, long n1,
    long n2) {
  long i = (long)blockIdx.x * blockDim.x + threadIdx.x;
  long stride = (long)gridDim.x * blockDim.x;
  const long ntot = n0 + n1 + n2;
  uint2* d4 = (uint2*)dst;
  for (; i < ntot; i += stride) {
    const float4* s4;
    long j;
    if (i < n0) {
      s4 = (const float4*)s0;
      j = i;
    } else if (i < n0 + n1) {
      s4 = (const float4*)s1;
      j = i - n0;
    } else {
      s4 = (const float4*)s2;
      j = i - n0 - n1;
    }
    float4 v = s4[j];
    uint2 o;
    o.x = (u32)f2bf(v.x) | ((u32)f2bf(v.y) << 16);
    o.y = (u32)f2bf(v.z) | ((u32)f2bf(v.w) << 16);
    d4[i] = o;
  }
}

// ============ GEMM1 fused: hidden = silu(x@Wg^T) * (x@Wu^T) ============
// Tile 128 rows x 128 hidden, BK=64, ring-3 LDS, counted vmcnt (round-2
// proven structure). 8 waves: wr=w>>2 (2x64 rows), wc=w&3 (4x32 hid cols).
// MFMA 32x32x16: per wave per K-tile 16 ds_read_b128 -> 16 MFMA.

__global__ __launch_bounds__(512) void gemm1_silu(const u16* __restrict__ Xb,
                                                  const u16* __restrict__ Wgu,
                                                  u16* __restrict__ Hid,
                                                  long sX, long sW, long sH) {
  const int z = blockIdx.z;
  Xb += (long)z * sX;
  Wgu += (long)z * sW;
  Hid += (long)z * sH;

  const int bx = blockIdx.x;  // hidden-col tile (128)
  const int by = blockIdx.y;  // row tile (128)
  const int tid = threadIdx.x;
  const int w = tid >> 6;
  const int lane = tid & 63;
  const int wr = w >> 2, wc = w & 3;
  const int l31 = lane & 31, q2 = lane >> 5, l7 = lane & 7;

  // per-buf: A[128][64] (8192 el) + Bg[128][64] + Bu[128][64]
  __shared__ __attribute__((aligned(16))) u16 lds[3 * 24576];

  // staging (unchanged, proven): LDS[r][g] holds global k-seg g^(r&7)
  const int srow = (w << 3) + (lane >> 3);
  const int scol = (((lane & 7) ^ (lane >> 3)) << 3);
  const u16* gA = Xb + (size_t)((by << 7) + srow) * H_ + scol;
  const u16* gBg = Wgu + (size_t)((bx << 7) + srow) * H_ + scol;
  const u16* gBu = gBg + (size_t)F_ * H_;

  auto stage = [&](int t, int buf) {
    u16* L = &lds[buf * 24576];
    const int ko = t << 6;
    const int wb = w << 3;
#pragma unroll
    for (int i = 0; i < 2; ++i) {
      gload16(gA + (size_t)(i * 64) * H_ + ko, &L[((i << 6) + wb) << 6]);
      gload16(gBg + (size_t)(i * 64) * H_ + ko,
              &L[8192 + (((i << 6) + wb) << 6)]);
      gload16(gBu + (size_t)(i * 64) * H_ + ko,
              &L[16384 + (((i << 6) + wb) << 6)]);
    }
  };

  f32x16 accG[2] = {};
  f32x16 accU[2] = {};

  auto comp = [&](int buf) {
    const u16* L = &lds[buf * 24576];
#pragma unroll
    for (int ks = 0; ks < 4; ++ks) {
      const int seg = (((ks << 1) + q2) ^ l7) << 3;
      bf16x8 a0 = *(const bf16x8*)&L[((wr << 6) + l31) * 64 + seg];
      bf16x8 a1 = *(const bf16x8*)&L[((wr << 6) + 32 + l31) * 64 + seg];
      bf16x8 bg = *(const bf16x8*)&L[8192 + ((wc << 5) + l31) * 64 + seg];
      bf16x8 bu = *(const bf16x8*)&L[16384 + ((wc << 5) + l31) * 64 + seg];
      __builtin_amdgcn_s_setprio(1);
      mfma32(accG[0], a0, bg);
      mfma32(accU[0], a0, bu);
      mfma32(accG[1], a1, bg);
      mfma32(accU[1], a1, bu);
      __builtin_amdgcn_s_setprio(0);
    }
  };

  const int NT = H_ / 64;  // 32
  stage(0, 0);
  stage(1, 1);
  int b0 = 0, b1 = 1, b2 = 2;
  for (int t = 0; t < NT - 2; ++t) {
    stage(t + 2, b2);
    WAITV(12);
    BARF;
    comp(b0);
    BARF;
    int tmp = b0; b0 = b1; b1 = b2; b2 = tmp;
  }
  WAITV(6); BARF;
  comp(b0);
  BARF;
  WAITV(0); BARF;
  comp(b1);

  // epilogue: silu(gate)*up -> bf16
  const int row0 = (by << 7) + (wr << 6);
  const int col = (bx << 7) + (wc << 5) + l31;
#pragma unroll
  for (int mi = 0; mi < 2; ++mi)
#pragma unroll
    for (int r = 0; r < 16; ++r) {
      const int trow = row0 + mi * 32 + (r & 3) + ((r >> 2) << 3) + (q2 << 2);
      float g = accG[mi][r];
      float u = accU[mi][r];
      float h = (g / (1.f + __expf(-g))) * u;
      Hid[(size_t)trow * F_ + col] = f2bf(h);
    }
}

// ============ GEMM2: out = hidden @ w_down^T (fp32 out) ============
// Tile 256 rows x 128 cols, BK=64, ring-3 (proven structure), 32x32x16 MFMA.
// 8 waves: wr=w>>1 (4x64 rows), wc=w&1 (2x64 cols).

__global__ __launch_bounds__(512) void gemm2_down(const u16* __restrict__ Hd,
                                                  const u16* __restrict__ Wd,
                                                  float* __restrict__ Out,
                                                  long sH, long sW, long sO) {
  const int z = blockIdx.z;
  Hd += (long)z * sH;
  Wd += (long)z * sW;
  Out += (long)z * sO;

  const int bx = blockIdx.x;  // H-col tile (128)
  const int by = blockIdx.y;  // row tile (256)
  const int tid = threadIdx.x;
  const int w = tid >> 6;
  const int lane = tid & 63;
  const int wr = w >> 1, wc = w & 1;
  const int l31 = lane & 31, q2 = lane >> 5, l7 = lane & 7;

  // per-buf: A[256][64] (16384 el) + B[128][64] (8192 el)
  __shared__ __attribute__((aligned(16))) u16 lds[3 * 24576];

  const int srow = (w << 3) + (lane >> 3);
  const int scol = (((lane & 7) ^ (lane >> 3)) << 3);
  const u16* gA = Hd + (size_t)((by << 8) + srow) * F_ + scol;
  const u16* gB = Wd + (size_t)((bx << 7) + srow) * F_ + scol;

  auto stage = [&](int t, int buf) {
    u16* L = &lds[buf * 24576];
    const int ko = t << 6;
    const int wb = w << 3;
#pragma unroll
    for (int i = 0; i < 4; ++i)
      gload16(gA + (size_t)(i * 64) * F_ + ko, &L[((i << 6) + wb) << 6]);
#pragma unroll
    for (int i = 0; i < 2; ++i)
      gload16(gB + (size_t)(i * 64) * F_ + ko,
              &L[16384 + (((i << 6) + wb) << 6)]);
  };

  f32x16 acc[2][2] = {};

  auto comp = [&](int buf) {
    const u16* L = &lds[buf * 24576];
#pragma unroll
    for (int ks = 0; ks < 4; ++ks) {
      const int seg = (((ks << 1) + q2) ^ l7) << 3;
      bf16x8 a0 = *(const bf16x8*)&L[((wr << 6) + l31) * 64 + seg];
      bf16x8 a1 = *(const bf16x8*)&L[((wr << 6) + 32 + l31) * 64 + seg];
      bf16x8 b0 = *(const bf16x8*)&L[16384 + ((wc << 6) + l31) * 64 + seg];
      bf16x8 b1 = *(const bf16x8*)&L[16384 + ((wc << 6) + 32 + l31) * 64 + seg];
      __builtin_amdgcn_s_setprio(1);
      mfma32(acc[0][0], a0, b0);
      mfma32(acc[0][1], a0, b1);
      mfma32(acc[1][0], a1, b0);
      mfma32(acc[1][1], a1, b1);
      __builtin_amdgcn_s_setprio(0);
    }
  };

  const int NT = F_ / 64;  // 64
  stage(0, 0);
  stage(1, 1);
  int b0 = 0, b1 = 1, b2 = 2;
  for (int t = 0; t < NT - 2; ++t) {
    stage(t + 2, b2);
    WAITV(12);
    BARF;
    comp(b0);
    BARF;
    int tmp = b0; b0 = b1; b1 = b2; b2 = tmp;
  }
  WAITV(6); BARF;
  comp(b0);
  BARF;
  WAITV(0); BARF;
  comp(b1);

  const int row0 = (by << 8) + (wr << 6);
  const int col0 = (bx << 7) + (wc << 6);
#pragma unroll
  for (int mi = 0; mi < 2; ++mi)
#pragma unroll
    for (int ni = 0; ni < 2; ++ni)
#pragma unroll
      for (int r = 0; r < 16; ++r) {
        const int trow =
            row0 + mi * 32 + (r & 3) + ((r >> 2) << 3) + (q2 << 2);
        const int tcol = col0 + ni * 32 + l31;
        Out[(size_t)trow * H_ + tcol] = acc[mi][ni][r];
      }
}

// ---------- host ----------

extern "C" void kernel_launch(void* const* d_in, const int* in_sizes, int n_in,
                              void* d_out, int out_size, void* d_ws,
                              size_t ws_size, hipStream_t stream) {
  (void)in_sizes;
  (void)n_in;
  (void)out_size;
  const float* x = (const float*)d_in[0];
  const float* wgu = (const float*)d_in[1];
  const float* wdn = (const float*)d_in[2];
  float* out = (float*)d_out;
  u16* ws = (u16*)d_ws;

  const size_t xbN = (size_t)T_ * H_;
  const size_t wguN = (size_t)E_ * 2 * F_ * H_;
  const size_t wdnN = (size_t)E_ * H_ * F_;
  const size_t hidN = (size_t)T_ * F_;
  const size_t fullBytes = (xbN + wguN + wdnN + hidN) * 2;  // 576 MiB

  dim3 cblk(256), gblk(512);

  if (ws_size >= fullBytes) {
    u16* xb = ws;
    u16* wgub = xb + xbN;
    u16* wdnb = wgub + wguN;
    u16* hid = wdnb + wdnN;
    cvt3_kernel<<<4096, cblk, 0, stream>>>(x, wgu, wdn, ws, (long)(xbN / 4),
                                           (long)(wguN / 4), (long)(wdnN / 4));
    gemm1_silu<<<dim3(F_ / 128, TE_ / 128, E_), gblk, 0, stream>>>(
        xb, wgub, hid, (long)TE_ * H_, (long)2 * F_ * H_, (long)TE_ * F_);
    gemm2_down<<<dim3(H_ / 128, TE_ / 256, E_), gblk, 0, stream>>>(
        hid, wdnb, out, (long)TE_ * F_, (long)H_ * F_, (long)TE_ * H_);
  } else {
    u16* xb = ws;
    u16* wgub = xb + (size_t)TE_ * H_;
    u16* wdnb = wgub + (size_t)2 * F_ * H_;
    u16* hid = wdnb + (size_t)H_ * F_;
    for (int e = 0; e < E_; ++e) {
      cvt3_kernel<<<2048, cblk, 0, stream>>>(
          x + (size_t)e * TE_ * H_, wgu + (size_t)e * 2 * F_ * H_,
          wdn + (size_t)e * H_ * F_, ws, (long)((size_t)TE_ * H_ / 4),
          (long)((size_t)2 * F_ * H_ / 4), (long)((size_t)H_ * F_ / 4));
      gemm1_silu<<<dim3(F_ / 128, TE_ / 128, 1), gblk, 0, stream>>>(xb, wgub,
                                                                    hid, 0, 0,
                                                                    0);
      gemm2_down<<<dim3(H_ / 128, TE_ / 256, 1), gblk, 0, stream>>>(
          hid, wdnb, out + (size_t)e * TE_ * H_, 0, 0, 0);
    }
  }
}

// Round 7
// 1096.660 us; speedup vs baseline: 1.1140x; 1.0714x over previous
//
#include <hip/hip_runtime.h>
#include <stdint.h>

typedef unsigned short u16;
typedef unsigned int u32;
typedef short bf16x8 __attribute__((ext_vector_type(8)));
typedef float f32x4 __attribute__((ext_vector_type(4)));

#define E_ 8
#define H_ 2048
#define F_ 4096
#define T_ 16384
#define TE_ 2048

#define WAITV(n) asm volatile("s_waitcnt vmcnt(" #n ")" ::: "memory")
#define BARF                       \
  do {                             \
    asm volatile("" ::: "memory"); \
    __builtin_amdgcn_s_barrier();  \
    asm volatile("" ::: "memory"); \
  } while (0)

__device__ __forceinline__ u16 f2bf(float f) {
  u32 u = __builtin_bit_cast(u32, f);
  u32 r = (u + 0x7FFFu + ((u >> 16) & 1u)) >> 16;  // RNE
  return (u16)r;
}

__device__ __forceinline__ void gload16(const u16* g, u16* l) {
  __builtin_amdgcn_global_load_lds(
      (__attribute__((address_space(1))) void*)g,
      (__attribute__((address_space(3))) void*)l, 16, 0, 0);
}

__device__ __forceinline__ void mfma_b(f32x4& acc, bf16x8 a, bf16x8 b) {
  asm volatile("v_mfma_f32_16x16x32_bf16 %0, %1, %2, %0"
               : "+v"(acc)
               : "v"(a), "v"(b));
}

// ---------- fused fp32 -> bf16 convert (3 segments, 1 launch) ----------

__global__ __launch_bounds__(256) void cvt3_kernel(
    const float* __restrict__ s0, const float* __restrict__ s1,
    const float* __restrict__ s2, u16* __restrict__ dst, long n0, long n1,
    long n2) {
  long i = (long)blockIdx.x * blockDim.x + threadIdx.x;
  long stride = (long)gridDim.x * blockDim.x;
  const long ntot = n0 + n1 + n2;
  uint2* d4 = (uint2*)dst;
  for (; i < ntot; i += stride) {
    const float4* s4;
    long j;
    if (i < n0) {
      s4 = (const float4*)s0;
      j = i;
    } else if (i < n0 + n1) {
      s4 = (const float4*)s1;
      j = i - n0;
    } else {
      s4 = (const float4*)s2;
      j = i - n0 - n1;
    }
    float4 v = s4[j];
    uint2 o;
    o.x = (u32)f2bf(v.x) | ((u32)f2bf(v.y) << 16);
    o.y = (u32)f2bf(v.z) | ((u32)f2bf(v.w) << 16);
    d4[i] = o;
  }
}

// ============ GEMM1 fused: hidden = silu(x@Wg^T) * (x@Wu^T) ============
// 256-thread / 4-wave blocks, tile 128 rows x 64 hidden cols, BK=64,
// ring-2 LDS = 64 KiB -> 2 blocks/CU (two independent barrier domains:
// one block's stage/barrier overlaps the other's MFMA, m114 mechanism).
// Waves 2x2: wr=w>>1 (64 rows), wc=w&1 (32 hidden cols). Per K-tile per
// wave: 8 gload16 staged, 16 ds_read_b128, 32 MFMA 16x16x32. Layout and
// XOR swizzle identical to the proven round-2 kernel (0 conflicts).

__global__ __launch_bounds__(256, 2) void gemm1_silu(
    const u16* __restrict__ Xb, const u16* __restrict__ Wgu,
    u16* __restrict__ Hid, long sX, long sW, long sH) {
  const int z = blockIdx.z;
  Xb += (long)z * sX;
  Wgu += (long)z * sW;
  Hid += (long)z * sH;

  const int bx = blockIdx.x;  // hidden-col tile (64)
  const int by = blockIdx.y;  // row tile (128)
  const int tid = threadIdx.x;
  const int w = tid >> 6;  // 0..3
  const int lane = tid & 63;
  const int wr = w >> 1, wc = w & 1;
  const int fr = lane & 15, q = lane >> 4, l7 = lane & 7;

  // per-buf (16384 el = 32 KB): A[128][64] @0, Bg[64][64] @8192, Bu @12288
  __shared__ __attribute__((aligned(16))) u16 lds[2 * 16384];

  // staging: chunk = 8 rows x 64 el (1 KB). LDS[row][p] = global[row][p^(row&7)]
  const int srow8 = lane >> 3;                 // row within chunk
  const int sgran = (lane & 7) ^ (lane >> 3);  // pre-swizzled source granule
  const u16* gA = Xb + (size_t)(by * 128 + srow8) * H_ + sgran * 8;
  const u16* gBg = Wgu + (size_t)(bx * 64 + srow8) * H_ + sgran * 8;
  const u16* gBu = gBg + (size_t)F_ * H_;

  auto stage = [&](int t, int buf) {
    u16* L = lds + buf * 16384;
    const int ko = t * 64;
#pragma unroll
    for (int i = 0; i < 4; ++i) {  // A: 16 chunks, 4 per wave
      const int c = i * 4 + w;
      gload16(gA + (size_t)(c * 8) * H_ + ko, L + c * 512 + lane * 8);
    }
#pragma unroll
    for (int i = 0; i < 2; ++i) {  // Bg, Bu: 8 chunks each, 2 per wave
      const int c = i * 4 + w;
      gload16(gBg + (size_t)(c * 8) * H_ + ko, L + 8192 + c * 512 + lane * 8);
      gload16(gBu + (size_t)(c * 8) * H_ + ko, L + 12288 + c * 512 + lane * 8);
    }
  };

  f32x4 accG[4][2] = {};
  f32x4 accU[4][2] = {};

  auto comp = [&](int buf) {
    const u16* L = lds + buf * 16384;
#pragma unroll
    for (int ks = 0; ks < 2; ++ks) {
      const int seg = (((ks << 2) + q) ^ l7) << 3;
      bf16x8 a[4], bg[2], bu[2];
#pragma unroll
      for (int mi = 0; mi < 4; ++mi)
        a[mi] = *(const bf16x8*)&L[(wr * 64 + mi * 16 + fr) * 64 + seg];
#pragma unroll
      for (int ni = 0; ni < 2; ++ni) {
        bg[ni] = *(const bf16x8*)&L[8192 + (wc * 32 + ni * 16 + fr) * 64 + seg];
        bu[ni] =
            *(const bf16x8*)&L[12288 + (wc * 32 + ni * 16 + fr) * 64 + seg];
      }
      __builtin_amdgcn_s_setprio(1);
#pragma unroll
      for (int mi = 0; mi < 4; ++mi)
#pragma unroll
        for (int ni = 0; ni < 2; ++ni) {
          mfma_b(accG[mi][ni], a[mi], bg[ni]);
          mfma_b(accU[mi][ni], a[mi], bu[ni]);
        }
      __builtin_amdgcn_s_setprio(0);
    }
  };

  const int NT = H_ / 64;  // 32
  stage(0, 0);
  stage(1, 1);
  for (int t = 0; t < NT - 1; ++t) {
    WAITV(8);  // tile t resident; tile t+1 (8 loads) stays in flight
    BARF;
    comp(t & 1);
    BARF;  // all waves done reading buf (t&1) -> safe to restage
    if (t + 2 < NT) stage(t + 2, t & 1);
  }
  WAITV(0);
  BARF;
  comp((NT - 1) & 1);

  // epilogue: silu(gate)*up -> bf16
  const int row0 = by * 128 + wr * 64 + q * 4;
  const int col0 = bx * 64 + wc * 32 + fr;
#pragma unroll
  for (int mi = 0; mi < 4; ++mi)
#pragma unroll
    for (int ni = 0; ni < 2; ++ni)
#pragma unroll
      for (int j = 0; j < 4; ++j) {
        float g = accG[mi][ni][j];
        float u = accU[mi][ni][j];
        float h = (g / (1.f + __expf(-g))) * u;
        Hid[(size_t)(row0 + mi * 16 + j) * F_ + col0 + ni * 16] = f2bf(h);
      }
}

// ---------- GEMM2: out = hidden @ w_down^T (fp32 out) ----------
// Tile 256x128, BK=64, ring-3 LDS, counted vmcnt, 16x16 MFMA (round-2
// proven, ~1060 TF).

__global__ __launch_bounds__(512) void gemm2_down(const u16* __restrict__ Hd,
                                                  const u16* __restrict__ Wd,
                                                  float* __restrict__ Out,
                                                  long sH, long sW, long sO) {
  const int z = blockIdx.z;
  Hd += (long)z * sH;
  Wd += (long)z * sW;
  Out += (long)z * sO;

  const int bx = blockIdx.x;  // H-col tile (128)
  const int by = blockIdx.y;  // row tile (256)
  const int tid = threadIdx.x;
  const int w = tid >> 6;
  const int lane = tid & 63;
  const int wr = w >> 1, wc = w & 1;

  // per-buf: A[256][64] (16384) + B[128][64] (8192)
  __shared__ __attribute__((aligned(16))) u16 lds[3 * 24576];

  const int srow = (w << 3) + (lane >> 3);
  const int scol = (((lane & 7) ^ (lane >> 3)) << 3);
  const u16* gA = Hd + (size_t)((by << 8) + srow) * F_ + scol;
  const u16* gB = Wd + (size_t)((bx << 7) + srow) * F_ + scol;

  auto stage = [&](int t, int buf) {
    u16* L = &lds[buf * 24576];
    const int ko = t << 6;
    const int wb = w << 3;
#pragma unroll
    for (int i = 0; i < 4; ++i)
      gload16(gA + (size_t)(i * 64) * F_ + ko, &L[((i << 6) + wb) << 6]);
#pragma unroll
    for (int i = 0; i < 2; ++i)
      gload16(gB + (size_t)(i * 64) * F_ + ko,
              &L[16384 + (((i << 6) + wb) << 6)]);
  };

  f32x4 acc[4][4] = {};
  const int fr = lane & 15, q = lane >> 4, l7 = lane & 7;

  auto comp = [&](int buf) {
    const u16* L = &lds[buf * 24576];
    bf16x8 a[4][2], b[4][2];
#pragma unroll
    for (int ni = 0; ni < 4; ++ni)
#pragma unroll
      for (int ks = 0; ks < 2; ++ks) {
        int r = (wc << 6) + (ni << 4) + fr;
        b[ni][ks] =
            *(const bf16x8*)&L[16384 + (r << 6) + ((((ks << 2) + q) ^ l7) << 3)];
      }
#pragma unroll
    for (int mi = 0; mi < 4; ++mi)
#pragma unroll
      for (int ks = 0; ks < 2; ++ks) {
        int r = (wr << 6) + (mi << 4) + fr;
        a[mi][ks] = *(const bf16x8*)&L[(r << 6) + ((((ks << 2) + q) ^ l7) << 3)];
      }
    __builtin_amdgcn_s_setprio(1);
#pragma unroll
    for (int mi = 0; mi < 4; ++mi)
#pragma unroll
      for (int ni = 0; ni < 4; ++ni)
#pragma unroll
        for (int ks = 0; ks < 2; ++ks)
          mfma_b(acc[mi][ni], a[mi][ks], b[ni][ks]);
    __builtin_amdgcn_s_setprio(0);
  };

  const int NT = F_ / 64;  // 64
  stage(0, 0);
  stage(1, 1);
  int b0 = 0, b1 = 1, b2 = 2;
  for (int t = 0; t < NT - 2; ++t) {
    stage(t + 2, b2);
    WAITV(12);
    BARF;
    comp(b0);
    BARF;
    int tmp = b0; b0 = b1; b1 = b2; b2 = tmp;
  }
  WAITV(6); BARF;
  comp(b0);
  BARF;
  WAITV(0); BARF;
  comp(b1);

  const int row0 = (by << 8) + (wr << 6) + (q << 2);
  const int col0 = (bx << 7) + (wc << 6) + fr;
#pragma unroll
  for (int mi = 0; mi < 4; ++mi)
#pragma unroll
    for (int ni = 0; ni < 4; ++ni)
#pragma unroll
      for (int j = 0; j < 4; ++j)
        Out[(size_t)(row0 + (mi << 4) + j) * H_ + col0 + (ni << 4)] =
            acc[mi][ni][j];
}

// ---------- host ----------

extern "C" void kernel_launch(void* const* d_in, const int* in_sizes, int n_in,
                              void* d_out, int out_size, void* d_ws,
                              size_t ws_size, hipStream_t stream) {
  (void)in_sizes;
  (void)n_in;
  (void)out_size;
  const float* x = (const float*)d_in[0];
  const float* wgu = (const float*)d_in[1];
  const float* wdn = (const float*)d_in[2];
  float* out = (float*)d_out;
  u16* ws = (u16*)d_ws;

  const size_t xbN = (size_t)T_ * H_;
  const size_t wguN = (size_t)E_ * 2 * F_ * H_;
  const size_t wdnN = (size_t)E_ * H_ * F_;
  const size_t hidN = (size_t)T_ * F_;
  const size_t fullBytes = (xbN + wguN + wdnN + hidN) * 2;  // 576 MiB

  dim3 cblk(256), g1blk(256), g2blk(512);

  if (ws_size >= fullBytes) {
    u16* xb = ws;
    u16* wgub = xb + xbN;
    u16* wdnb = wgub + wguN;
    u16* hid = wdnb + wdnN;
    cvt3_kernel<<<4096, cblk, 0, stream>>>(x, wgu, wdn, ws, (long)(xbN / 4),
                                           (long)(wguN / 4), (long)(wdnN / 4));
    gemm1_silu<<<dim3(F_ / 64, TE_ / 128, E_), g1blk, 0, stream>>>(
        xb, wgub, hid, (long)TE_ * H_, (long)2 * F_ * H_, (long)TE_ * F_);
    gemm2_down<<<dim3(H_ / 128, TE_ / 256, E_), g2blk, 0, stream>>>(
        hid, wdnb, out, (long)TE_ * F_, (long)H_ * F_, (long)TE_ * H_);
  } else {
    u16* xb = ws;
    u16* wgub = xb + (size_t)TE_ * H_;
    u16* wdnb = wgub + (size_t)2 * F_ * H_;
    u16* hid = wdnb + (size_t)H_ * F_;
    for (int e = 0; e < E_; ++e) {
      cvt3_kernel<<<2048, cblk, 0, stream>>>(
          x + (size_t)e * TE_ * H_, wgu + (size_t)e * 2 * F_ * H_,
          wdn + (size_t)e * H_ * F_, ws, (long)((size_t)TE_ * H_ / 4),
          (long)((size_t)2 * F_ * H_ / 4), (long)((size_t)H_ * F_ / 4));
      gemm1_silu<<<dim3(F_ / 64, TE_ / 128, 1), g1blk, 0, stream>>>(xb, wgub,
                                                                    hid, 0, 0,
                                                                    0);
      gemm2_down<<<dim3(H_ / 128, TE_ / 256, 1), g2blk, 0, stream>>>(
          hid, wdnb, out + (size_t)e * TE_ * H_, 0, 0, 0);
    }
  }
}

// Round 8
// 1074.119 us; speedup vs baseline: 1.1373x; 1.0210x over previous
//
#include <hip/hip_runtime.h>
#include <stdint.h>

typedef unsigned short u16;
typedef unsigned int u32;
typedef short bf16x8 __attribute__((ext_vector_type(8)));
typedef float f32x4 __attribute__((ext_vector_type(4)));

#define E_ 8
#define H_ 2048
#define F_ 4096
#define T_ 16384
#define TE_ 2048

#define WAITV(n) asm volatile("s_waitcnt vmcnt(" #n ")" ::: "memory")
#define BARF                       \
  do {                             \
    asm volatile("" ::: "memory"); \
    __builtin_amdgcn_s_barrier();  \
    asm volatile("" ::: "memory"); \
  } while (0)

__device__ __forceinline__ u16 f2bf(float f) {
  u32 u = __builtin_bit_cast(u32, f);
  u32 r = (u + 0x7FFFu + ((u >> 16) & 1u)) >> 16;  // RNE
  return (u16)r;
}

__device__ __forceinline__ void gload16(const u16* g, u16* l) {
  __builtin_amdgcn_global_load_lds(
      (__attribute__((address_space(1))) void*)g,
      (__attribute__((address_space(3))) void*)l, 16, 0, 0);
}

__device__ __forceinline__ void mfma_b(f32x4& acc, bf16x8 a, bf16x8 b) {
  asm volatile("v_mfma_f32_16x16x32_bf16 %0, %1, %2, %0"
               : "+v"(acc)
               : "v"(a), "v"(b));
}

// ---------- fp32 -> bf16 convert (3 separate launches, round-2 proven) ----

__global__ __launch_bounds__(256) void cvt_kernel(const float* __restrict__ src,
                                                  u16* __restrict__ dst,
                                                  long n4) {
  long i = (long)blockIdx.x * blockDim.x + threadIdx.x;
  long stride = (long)gridDim.x * blockDim.x;
  const float4* s4 = (const float4*)src;
  uint2* d4 = (uint2*)dst;
  for (; i < n4; i += stride) {
    float4 v = s4[i];
    uint2 o;
    o.x = (u32)f2bf(v.x) | ((u32)f2bf(v.y) << 16);
    o.y = (u32)f2bf(v.z) | ((u32)f2bf(v.w) << 16);
    d4[i] = o;
  }
}

// ============ GEMM1 fused: hidden = silu(x@Wg^T) * (x@Wu^T) ============
// (round-7 proven: 545us, MfmaUtil 48.6, 0 conflicts)
// 256-thread / 4-wave blocks, tile 128 rows x 64 hidden cols, BK=64,
// ring-2 LDS = 64 KiB -> 2 blocks/CU (two independent barrier domains).

__global__ __launch_bounds__(256, 2) void gemm1_silu(
    const u16* __restrict__ Xb, const u16* __restrict__ Wgu,
    u16* __restrict__ Hid, long sX, long sW, long sH) {
  const int z = blockIdx.z;
  Xb += (long)z * sX;
  Wgu += (long)z * sW;
  Hid += (long)z * sH;

  const int bx = blockIdx.x;  // hidden-col tile (64)
  const int by = blockIdx.y;  // row tile (128)
  const int tid = threadIdx.x;
  const int w = tid >> 6;  // 0..3
  const int lane = tid & 63;
  const int wr = w >> 1, wc = w & 1;
  const int fr = lane & 15, q = lane >> 4, l7 = lane & 7;

  // per-buf (16384 el = 32 KB): A[128][64] @0, Bg[64][64] @8192, Bu @12288
  __shared__ __attribute__((aligned(16))) u16 lds[2 * 16384];

  const int srow8 = lane >> 3;
  const int sgran = (lane & 7) ^ (lane >> 3);
  const u16* gA = Xb + (size_t)(by * 128 + srow8) * H_ + sgran * 8;
  const u16* gBg = Wgu + (size_t)(bx * 64 + srow8) * H_ + sgran * 8;
  const u16* gBu = gBg + (size_t)F_ * H_;

  auto stage = [&](int t, int buf) {
    u16* L = lds + buf * 16384;
    const int ko = t * 64;
#pragma unroll
    for (int i = 0; i < 4; ++i) {
      const int c = i * 4 + w;
      gload16(gA + (size_t)(c * 8) * H_ + ko, L + c * 512 + lane * 8);
    }
#pragma unroll
    for (int i = 0; i < 2; ++i) {
      const int c = i * 4 + w;
      gload16(gBg + (size_t)(c * 8) * H_ + ko, L + 8192 + c * 512 + lane * 8);
      gload16(gBu + (size_t)(c * 8) * H_ + ko, L + 12288 + c * 512 + lane * 8);
    }
  };

  f32x4 accG[4][2] = {};
  f32x4 accU[4][2] = {};

  auto comp = [&](int buf) {
    const u16* L = lds + buf * 16384;
#pragma unroll
    for (int ks = 0; ks < 2; ++ks) {
      const int seg = (((ks << 2) + q) ^ l7) << 3;
      bf16x8 a[4], bg[2], bu[2];
#pragma unroll
      for (int mi = 0; mi < 4; ++mi)
        a[mi] = *(const bf16x8*)&L[(wr * 64 + mi * 16 + fr) * 64 + seg];
#pragma unroll
      for (int ni = 0; ni < 2; ++ni) {
        bg[ni] = *(const bf16x8*)&L[8192 + (wc * 32 + ni * 16 + fr) * 64 + seg];
        bu[ni] =
            *(const bf16x8*)&L[12288 + (wc * 32 + ni * 16 + fr) * 64 + seg];
      }
      __builtin_amdgcn_s_setprio(1);
#pragma unroll
      for (int mi = 0; mi < 4; ++mi)
#pragma unroll
        for (int ni = 0; ni < 2; ++ni) {
          mfma_b(accG[mi][ni], a[mi], bg[ni]);
          mfma_b(accU[mi][ni], a[mi], bu[ni]);
        }
      __builtin_amdgcn_s_setprio(0);
    }
  };

  const int NT = H_ / 64;  // 32
  stage(0, 0);
  stage(1, 1);
  for (int t = 0; t < NT - 1; ++t) {
    WAITV(8);
    BARF;
    comp(t & 1);
    BARF;
    if (t + 2 < NT) stage(t + 2, t & 1);
  }
  WAITV(0);
  BARF;
  comp((NT - 1) & 1);

  const int row0 = by * 128 + wr * 64 + q * 4;
  const int col0 = bx * 64 + wc * 32 + fr;
#pragma unroll
  for (int mi = 0; mi < 4; ++mi)
#pragma unroll
    for (int ni = 0; ni < 2; ++ni)
#pragma unroll
      for (int j = 0; j < 4; ++j) {
        float g = accG[mi][ni][j];
        float u = accU[mi][ni][j];
        float h = (g / (1.f + __expf(-g))) * u;
        Hid[(size_t)(row0 + mi * 16 + j) * F_ + col0 + ni * 16] = f2bf(h);
      }
}

// ============ GEMM2: out = hidden @ w_down^T (fp32 out) ============
// Same m114 structure: 256-thread / 4-wave blocks, tile 128 rows x 128
// cols, wave tile 64x64, BK=64, ring-2 LDS = 64 KiB -> 2 blocks/CU.
// Per K-tile per wave: 8 gload16, 16 ds_read_b128, 32 MFMA 16x16x32.

__global__ __launch_bounds__(256, 2) void gemm2_down(
    const u16* __restrict__ Hd, const u16* __restrict__ Wd,
    float* __restrict__ Out, long sH, long sW, long sO) {
  const int z = blockIdx.z;
  Hd += (long)z * sH;
  Wd += (long)z * sW;
  Out += (long)z * sO;

  const int bx = blockIdx.x;  // H-col tile (128)
  const int by = blockIdx.y;  // row tile (128)
  const int tid = threadIdx.x;
  const int w = tid >> 6;  // 0..3
  const int lane = tid & 63;
  const int wr = w >> 1, wc = w & 1;
  const int fr = lane & 15, q = lane >> 4, l7 = lane & 7;

  // per-buf (16384 el = 32 KB): A[128][64] @0, B[128][64] @8192
  __shared__ __attribute__((aligned(16))) u16 lds[2 * 16384];

  const int srow8 = lane >> 3;
  const int sgran = (lane & 7) ^ (lane >> 3);
  const u16* gA = Hd + (size_t)(by * 128 + srow8) * F_ + sgran * 8;
  const u16* gB = Wd + (size_t)(bx * 128 + srow8) * F_ + sgran * 8;

  auto stage = [&](int t, int buf) {
    u16* L = lds + buf * 16384;
    const int ko = t * 64;
#pragma unroll
    for (int i = 0; i < 4; ++i) {
      const int c = i * 4 + w;
      gload16(gA + (size_t)(c * 8) * F_ + ko, L + c * 512 + lane * 8);
      gload16(gB + (size_t)(c * 8) * F_ + ko, L + 8192 + c * 512 + lane * 8);
    }
  };

  f32x4 acc[4][4] = {};

  auto comp = [&](int buf) {
    const u16* L = lds + buf * 16384;
#pragma unroll
    for (int ks = 0; ks < 2; ++ks) {
      const int seg = (((ks << 2) + q) ^ l7) << 3;
      bf16x8 a[4], b[4];
#pragma unroll
      for (int mi = 0; mi < 4; ++mi)
        a[mi] = *(const bf16x8*)&L[(wr * 64 + mi * 16 + fr) * 64 + seg];
#pragma unroll
      for (int ni = 0; ni < 4; ++ni)
        b[ni] = *(const bf16x8*)&L[8192 + (wc * 64 + ni * 16 + fr) * 64 + seg];
      __builtin_amdgcn_s_setprio(1);
#pragma unroll
      for (int mi = 0; mi < 4; ++mi)
#pragma unroll
        for (int ni = 0; ni < 4; ++ni) mfma_b(acc[mi][ni], a[mi], b[ni]);
      __builtin_amdgcn_s_setprio(0);
    }
  };

  const int NT = F_ / 64;  // 64
  stage(0, 0);
  stage(1, 1);
  for (int t = 0; t < NT - 1; ++t) {
    WAITV(8);
    BARF;
    comp(t & 1);
    BARF;
    if (t + 2 < NT) stage(t + 2, t & 1);
  }
  WAITV(0);
  BARF;
  comp((NT - 1) & 1);

  const int row0 = by * 128 + wr * 64 + q * 4;
  const int col0 = bx * 128 + wc * 64 + fr;
#pragma unroll
  for (int mi = 0; mi < 4; ++mi)
#pragma unroll
    for (int ni = 0; ni < 4; ++ni)
#pragma unroll
      for (int j = 0; j < 4; ++j)
        Out[(size_t)(row0 + mi * 16 + j) * H_ + col0 + ni * 16] =
            acc[mi][ni][j];
}

// ---------- host ----------

extern "C" void kernel_launch(void* const* d_in, const int* in_sizes, int n_in,
                              void* d_out, int out_size, void* d_ws,
                              size_t ws_size, hipStream_t stream) {
  (void)in_sizes;
  (void)n_in;
  (void)out_size;
  const float* x = (const float*)d_in[0];
  const float* wgu = (const float*)d_in[1];
  const float* wdn = (const float*)d_in[2];
  float* out = (float*)d_out;
  u16* ws = (u16*)d_ws;

  const size_t xbN = (size_t)T_ * H_;
  const size_t wguN = (size_t)E_ * 2 * F_ * H_;
  const size_t wdnN = (size_t)E_ * H_ * F_;
  const size_t hidN = (size_t)T_ * F_;
  const size_t fullBytes = (xbN + wguN + wdnN + hidN) * 2;  // 576 MiB

  dim3 cblk(256), gblk(256);

  if (ws_size >= fullBytes) {
    u16* xb = ws;
    u16* wgub = xb + xbN;
    u16* wdnb = wgub + wguN;
    u16* hid = wdnb + wdnN;
    cvt_kernel<<<2048, cblk, 0, stream>>>(x, xb, (long)(xbN / 4));
    cvt_kernel<<<4096, cblk, 0, stream>>>(wgu, wgub, (long)(wguN / 4));
    cvt_kernel<<<4096, cblk, 0, stream>>>(wdn, wdnb, (long)(wdnN / 4));
    gemm1_silu<<<dim3(F_ / 64, TE_ / 128, E_), gblk, 0, stream>>>(
        xb, wgub, hid, (long)TE_ * H_, (long)2 * F_ * H_, (long)TE_ * F_);
    gemm2_down<<<dim3(H_ / 128, TE_ / 128, E_), gblk, 0, stream>>>(
        hid, wdnb, out, (long)TE_ * F_, (long)H_ * F_, (long)TE_ * H_);
  } else {
    u16* xb = ws;
    u16* wgub = xb + (size_t)TE_ * H_;
    u16* wdnb = wgub + (size_t)2 * F_ * H_;
    u16* hid = wdnb + (size_t)H_ * F_;
    for (int e = 0; e < E_; ++e) {
      cvt_kernel<<<1024, cblk, 0, stream>>>(x + (size_t)e * TE_ * H_, xb,
                                            (long)((size_t)TE_ * H_ / 4));
      cvt_kernel<<<2048, cblk, 0, stream>>>(wgu + (size_t)e * 2 * F_ * H_, wgub,
                                            (long)((size_t)2 * F_ * H_ / 4));
      cvt_kernel<<<2048, cblk, 0, stream>>>(wdn + (size_t)e * H_ * F_, wdnb,
                                            (long)((size_t)H_ * F_ / 4));
      gemm1_silu<<<dim3(F_ / 64, TE_ / 128, 1), gblk, 0, stream>>>(xb, wgub,
                                                                   hid, 0, 0,
                                                                   0);
      gemm2_down<<<dim3(H_ / 128, TE_ / 128, 1), gblk, 0, stream>>>(
          hid, wdnb, out + (size_t)e * TE_ * H_, 0, 0, 0);
    }
  }
}